// Round 16
// baseline (313.069 us; speedup 1.0000x reference)
//
// rev r16 — GEMM occupancy fix: 32-row tiles (16 KB LDS, 2x blocks, 6.1/CU)
// vs r15's 64-row (29% occupancy, latency-bound: VALU 30%, HBM 21%).
// Everything else unchanged (one variable per round). r15: 298 µs.
#include <hip/hip_runtime.h>

typedef unsigned short u16;
typedef unsigned int   u32;

__device__ __forceinline__ float b2f(u16 h){ return __uint_as_float(((u32)h) << 16); }
__device__ __forceinline__ u16   f2b(float f){
  u32 u = __float_as_uint(f);
  u32 r = u + 0x7FFFu + ((u >> 16) & 1u);   // round-to-nearest-even
  return (u16)(r >> 16);
}
__device__ __forceinline__ float lo16(u32 w){ return b2f((u16)(w & 0xFFFFu)); }
__device__ __forceinline__ float hi16(u32 w){ return b2f((u16)(w >> 16)); }

// ---------------- CSR build (by dst); self-loops appended after real edges ----
__global__ void r16_zero(int* p, int n){
  int t = blockIdx.x*blockDim.x + threadIdx.x;
  if (t < n) p[t] = 0;
}

__global__ void r16_hist(const int* ei, int E, int Ep, int* cnt){
  int t = blockIdx.x*blockDim.x + threadIdx.x;
  if (t >= Ep) return;
  int dst = (t < E) ? ei[E + t] : (t - E);
  atomicAdd(&cnt[dst], 1);
}

__global__ void r16_scan1(const int* in, int n, int* incl, int* bsums){
  __shared__ int tmp[256];
  int t = threadIdx.x; int g = blockIdx.x*256 + t;
  int v = (g < n) ? in[g] : 0;
  tmp[t] = v; __syncthreads();
  for (int off = 1; off < 256; off <<= 1){
    int u = (t >= off) ? tmp[t - off] : 0;
    __syncthreads();
    tmp[t] += u;
    __syncthreads();
  }
  if (g < n) incl[g] = tmp[t];
  if (t == 255) bsums[blockIdx.x] = tmp[255];
}

__global__ void r16_scan2(int* bsums, int nb){
  __shared__ int tmp[256];
  int t = threadIdx.x;
  int v = (t < nb) ? bsums[t] : 0;
  tmp[t] = v; __syncthreads();
  for (int off = 1; off < 256; off <<= 1){
    int u = (t >= off) ? tmp[t - off] : 0;
    __syncthreads();
    tmp[t] += u;
    __syncthreads();
  }
  if (t < nb) bsums[t] = tmp[t];
}

__global__ void r16_scan3(const int* incl, const int* cnt, const int* bsums,
                          int n, int Nnodes, int* offs, int* cursor){
  int t = threadIdx.x; int b = blockIdx.x; int g = b*256 + t;
  if (g >= n) return;
  int add = (b > 0) ? bsums[b-1] : 0;
  int ex = incl[g] - cnt[g] + add;       // exclusive prefix
  offs[g] = ex;
  if (g < Nnodes) cursor[g] = ex;
}

// ---- GEMM body (32-row x 128-col tile; thread owns 4 rows x 4 cols) ----
__device__ __forceinline__ void r16_gemm_body(
    const float* __restrict__ X, const float* __restrict__ W,
    const float* __restrict__ atts, const float* __restrict__ attd,
    u16* __restrict__ HB, float* __restrict__ AS, float* __restrict__ AD,
    int nrows, int blk, float* xs){
  int t = threadIdx.x;
  int r0 = blk * 32;
  #pragma unroll
  for (int it = 0; it < 4; ++it){
    int idx = it*256 + t;        // float4 index; 32 per 128-elem row
    int row = idx >> 5;
    int c4  = (idx & 31) * 4;
    float4 v = {0.f,0.f,0.f,0.f};
    if (r0 + row < nrows) v = *(const float4*)(X + (size_t)(r0+row)*128 + c4);
    *(float4*)&xs[row*128 + c4] = v;
  }
  __syncthreads();

  int cgrp = t & 31, rgrp = t >> 5;   // 8 rgrps x 4 rows
  int col0 = cgrp * 4;
  float acc[4][4];
  #pragma unroll
  for (int r = 0; r < 4; ++r){
    #pragma unroll
    for (int j = 0; j < 4; ++j) acc[r][j] = 0.f;
  }
  #pragma unroll 2
  for (int k = 0; k < 128; k += 4){
    float4 w0 = *(const float4*)(W + (size_t)(k+0)*128 + col0);
    float4 w1 = *(const float4*)(W + (size_t)(k+1)*128 + col0);
    float4 w2 = *(const float4*)(W + (size_t)(k+2)*128 + col0);
    float4 w3 = *(const float4*)(W + (size_t)(k+3)*128 + col0);
    float4 xr[4];
    #pragma unroll
    for (int r = 0; r < 4; ++r) xr[r] = *(const float4*)&xs[(rgrp*4 + r)*128 + k];
    #pragma unroll
    for (int r = 0; r < 4; ++r){
      acc[r][0] = fmaf(xr[r].x, w0.x, acc[r][0]);
      acc[r][1] = fmaf(xr[r].x, w0.y, acc[r][1]);
      acc[r][2] = fmaf(xr[r].x, w0.z, acc[r][2]);
      acc[r][3] = fmaf(xr[r].x, w0.w, acc[r][3]);
      acc[r][0] = fmaf(xr[r].y, w1.x, acc[r][0]);
      acc[r][1] = fmaf(xr[r].y, w1.y, acc[r][1]);
      acc[r][2] = fmaf(xr[r].y, w1.z, acc[r][2]);
      acc[r][3] = fmaf(xr[r].y, w1.w, acc[r][3]);
      acc[r][0] = fmaf(xr[r].z, w2.x, acc[r][0]);
      acc[r][1] = fmaf(xr[r].z, w2.y, acc[r][1]);
      acc[r][2] = fmaf(xr[r].z, w2.z, acc[r][2]);
      acc[r][3] = fmaf(xr[r].z, w2.w, acc[r][3]);
      acc[r][0] = fmaf(xr[r].w, w3.x, acc[r][0]);
      acc[r][1] = fmaf(xr[r].w, w3.y, acc[r][1]);
      acc[r][2] = fmaf(xr[r].w, w3.z, acc[r][2]);
      acc[r][3] = fmaf(xr[r].w, w3.w, acc[r][3]);
    }
  }
  float4 sv = *(const float4*)(atts + col0);
  float4 dv = *(const float4*)(attd + col0);
  #pragma unroll
  for (int r = 0; r < 4; ++r){
    int row = r0 + rgrp*4 + r;
    float ps = acc[r][0]*sv.x + acc[r][1]*sv.y + acc[r][2]*sv.z + acc[r][3]*sv.w;
    float pd = acc[r][0]*dv.x + acc[r][1]*dv.y + acc[r][2]*dv.z + acc[r][3]*dv.w;
    #pragma unroll
    for (int off = 16; off >= 1; off >>= 1){  // reduce within 32-lane cohort
      ps += __shfl_xor(ps, off);
      pd += __shfl_xor(pd, off);
    }
    if (row < nrows){
      uint2 pb;
      pb.x = (u32)f2b(acc[r][0]) | ((u32)f2b(acc[r][1]) << 16);
      pb.y = (u32)f2b(acc[r][2]) | ((u32)f2b(acc[r][3]) << 16);
      *(uint2*)&HB[(size_t)row*128 + col0] = pb;
      if (cgrp == 0){ AS[row] = ps; AD[row] = pd; }
    }
  }
}

// FAT: blocks [0,gemmBlocks) = GEMM+dots; rest = CSR fill (co-scheduled)
__global__ __launch_bounds__(256)
void r16_gemm_fill(const float* __restrict__ X, const float* __restrict__ W,
                   const float* __restrict__ atts, const float* __restrict__ attd,
                   u16* __restrict__ HB, float* __restrict__ AS, float* __restrict__ AD,
                   int nrows, int gemmBlocks,
                   const int* __restrict__ ei, int E, int Ep,
                   int* cursor, int* csr_src){
  __shared__ float xs[32*128];   // 16 KB
  if ((int)blockIdx.x >= gemmBlocks){
    int g = ((int)blockIdx.x - gemmBlocks)*256 + threadIdx.x;
    if (g < Ep){
      int src, dst;
      if (g < E){ src = ei[g]; dst = ei[E + g]; } else { src = g - E; dst = g - E; }
      int pos = atomicAdd(&cursor[dst], 1);
      csr_src[pos] = src;
    }
    return;
  }
  r16_gemm_body(X, W, atts, attd, HB, AS, AD, nrows, blockIdx.x, xs);
}

__global__ __launch_bounds__(256)
void r16_gemm(const float* __restrict__ X, const float* __restrict__ W,
              const float* __restrict__ atts, const float* __restrict__ attd,
              u16* __restrict__ HB, float* __restrict__ AS, float* __restrict__ AD,
              int nrows){
  __shared__ float xs[32*128];   // 16 KB
  r16_gemm_body(X, W, atts, attd, HB, AS, AD, nrows, blockIdx.x, xs);
}

// ---- segment softmax + aggregation (one wave / dst node), gather unroll x8 ----
__global__ __launch_bounds__(256)
void r16_aggregate(const u16* __restrict__ HB, const float* __restrict__ AS,
                   const float* __restrict__ AD,
                   const int* __restrict__ offs, const int* __restrict__ csr,
                   const float* __restrict__ bias,
                   const float* __restrict__ gamma_, const float* __restrict__ beta_,
                   const float* __restrict__ mean_, const float* __restrict__ var_,
                   float* __restrict__ outp, int n, int doBN){
  int wid  = (blockIdx.x*256 + threadIdx.x) >> 6;
  int lane = threadIdx.x & 63;
  if (wid >= n) return;
  int beg = offs[wid], end = offs[wid+1];
  int deg = end - beg;
  float ad = AD[wid];
  int c2 = lane*2;
  float a0 = 0.f, a1 = 0.f;

  if (deg <= 64){
    int   my_s = 0;
    float my_e = -3.0e38f;
    int myk = beg + lane;
    bool act = (myk < end);
    if (act){
      my_s = csr[myk];
      float e = AS[my_s] + ad;
      my_e = (e > 0.f) ? e : 0.2f*e;
    }
    float m = my_e;
    #pragma unroll
    for (int off = 32; off >= 1; off >>= 1) m = fmaxf(m, __shfl_xor(m, off));
    float pz = act ? __expf(my_e - m) : 0.f;
    float den = pz;
    #pragma unroll
    for (int off = 32; off >= 1; off >>= 1) den += __shfl_xor(den, off);
    float my_al = pz / (den + 1e-16f);

    int j = 0;
    for (; j + 8 <= deg; j += 8){
      int   s0 = __shfl(my_s, j),   s1 = __shfl(my_s, j+1);
      int   s2 = __shfl(my_s, j+2), s3 = __shfl(my_s, j+3);
      int   s4 = __shfl(my_s, j+4), s5 = __shfl(my_s, j+5);
      int   s6 = __shfl(my_s, j+6), s7 = __shfl(my_s, j+7);
      float l0 = __shfl(my_al, j),   l1 = __shfl(my_al, j+1);
      float l2 = __shfl(my_al, j+2), l3 = __shfl(my_al, j+3);
      float l4 = __shfl(my_al, j+4), l5 = __shfl(my_al, j+5);
      float l6 = __shfl(my_al, j+6), l7 = __shfl(my_al, j+7);
      u32 h0 = *(const u32*)&HB[(size_t)s0*128 + c2];
      u32 h1 = *(const u32*)&HB[(size_t)s1*128 + c2];
      u32 h2 = *(const u32*)&HB[(size_t)s2*128 + c2];
      u32 h3 = *(const u32*)&HB[(size_t)s3*128 + c2];
      u32 h4 = *(const u32*)&HB[(size_t)s4*128 + c2];
      u32 h5 = *(const u32*)&HB[(size_t)s5*128 + c2];
      u32 h6 = *(const u32*)&HB[(size_t)s6*128 + c2];
      u32 h7 = *(const u32*)&HB[(size_t)s7*128 + c2];
      a0 = fmaf(l0, lo16(h0), a0); a1 = fmaf(l0, hi16(h0), a1);
      a0 = fmaf(l1, lo16(h1), a0); a1 = fmaf(l1, hi16(h1), a1);
      a0 = fmaf(l2, lo16(h2), a0); a1 = fmaf(l2, hi16(h2), a1);
      a0 = fmaf(l3, lo16(h3), a0); a1 = fmaf(l3, hi16(h3), a1);
      a0 = fmaf(l4, lo16(h4), a0); a1 = fmaf(l4, hi16(h4), a1);
      a0 = fmaf(l5, lo16(h5), a0); a1 = fmaf(l5, hi16(h5), a1);
      a0 = fmaf(l6, lo16(h6), a0); a1 = fmaf(l6, hi16(h6), a1);
      a0 = fmaf(l7, lo16(h7), a0); a1 = fmaf(l7, hi16(h7), a1);
    }
    for (; j + 4 <= deg; j += 4){
      int   s0 = __shfl(my_s, j),   s1 = __shfl(my_s, j+1);
      int   s2 = __shfl(my_s, j+2), s3 = __shfl(my_s, j+3);
      float l0 = __shfl(my_al, j),   l1 = __shfl(my_al, j+1);
      float l2 = __shfl(my_al, j+2), l3 = __shfl(my_al, j+3);
      u32 h0 = *(const u32*)&HB[(size_t)s0*128 + c2];
      u32 h1 = *(const u32*)&HB[(size_t)s1*128 + c2];
      u32 h2 = *(const u32*)&HB[(size_t)s2*128 + c2];
      u32 h3 = *(const u32*)&HB[(size_t)s3*128 + c2];
      a0 = fmaf(l0, lo16(h0), a0); a1 = fmaf(l0, hi16(h0), a1);
      a0 = fmaf(l1, lo16(h1), a0); a1 = fmaf(l1, hi16(h1), a1);
      a0 = fmaf(l2, lo16(h2), a0); a1 = fmaf(l2, hi16(h2), a1);
      a0 = fmaf(l3, lo16(h3), a0); a1 = fmaf(l3, hi16(h3), a1);
    }
    for (; j < deg; ++j){
      int   s = __shfl(my_s, j);
      float l = __shfl(my_al, j);
      u32 hv = *(const u32*)&HB[(size_t)s*128 + c2];
      a0 = fmaf(l, lo16(hv), a0); a1 = fmaf(l, hi16(hv), a1);
    }
  } else {
    float m = -3.0e38f;
    for (int k = beg + lane; k < end; k += 64){
      int s = csr[k];
      float e = AS[s] + ad; e = (e > 0.f) ? e : 0.2f*e;
      m = fmaxf(m, e);
    }
    #pragma unroll
    for (int off = 32; off >= 1; off >>= 1) m = fmaxf(m, __shfl_xor(m, off));
    float den = 0.f;
    for (int k = beg + lane; k < end; k += 64){
      int s = csr[k];
      float e = AS[s] + ad; e = (e > 0.f) ? e : 0.2f*e;
      den += __expf(e - m);
    }
    #pragma unroll
    for (int off = 32; off >= 1; off >>= 1) den += __shfl_xor(den, off);
    float inv = 1.0f / (den + 1e-16f);
    for (int k = beg; k < end; ++k){
      int s = csr[k];
      float e = AS[s] + ad; e = (e > 0.f) ? e : 0.2f*e;
      float al = __expf(e - m) * inv;
      u32 hv = *(const u32*)&HB[(size_t)s*128 + c2];
      a0 = fmaf(al, lo16(hv), a0); a1 = fmaf(al, hi16(hv), a1);
    }
  }

  float v0 = a0 + bias[c2];
  float v1 = a1 + bias[c2+1];
  v0 = fmaxf(v0, 0.f); v1 = fmaxf(v1, 0.f);            // relu
  if (doBN){
    float s0 = gamma_[c2]   * rsqrtf(var_[c2]   + 1e-5f);
    float s1 = gamma_[c2+1] * rsqrtf(var_[c2+1] + 1e-5f);
    v0 = (v0 - mean_[c2])*s0   + beta_[c2];
    v1 = (v1 - mean_[c2+1])*s1 + beta_[c2+1];
  }
  float2 o = {v0, v1};
  ((float2*)(outp + (size_t)wid*128))[lane] = o;
}

extern "C" void kernel_launch(void* const* d_in, const int* in_sizes, int n_in,
                              void* d_out, int out_size, void* d_ws, size_t ws_size,
                              hipStream_t stream){
  const float* x   = (const float*)d_in[0];
  const int*   ei  = (const int*)  d_in[1];
  const float* W1  = (const float*)d_in[2];
  const float* as1 = (const float*)d_in[3];
  const float* ad1 = (const float*)d_in[4];
  const float* b1  = (const float*)d_in[5];
  const float* bng = (const float*)d_in[6];
  const float* bnb = (const float*)d_in[7];
  const float* bnm = (const float*)d_in[8];
  const float* bnv = (const float*)d_in[9];
  const float* W2  = (const float*)d_in[10];
  const float* as2 = (const float*)d_in[11];
  const float* ad2 = (const float*)d_in[12];
  const float* b2  = (const float*)d_in[13];
  float* out = (float*)d_out;

  int N  = in_sizes[0] / 128;
  int E  = in_sizes[1] / 2;
  int Ep = E + N;
  if (N <= 0 || E <= 0) return;

  // workspace (~43 MB of 256 MB), 256 B-aligned
  char* base = (char*)d_ws;
  size_t off = 0;
  auto alloc = [&](size_t bytes)->char*{
    off = (off + 255) & ~(size_t)255;
    char* q = base + off; off += bytes; return q;
  };
  float* AS     = (float*)alloc((size_t)N*4);
  float* AD     = (float*)alloc((size_t)N*4);
  int*   cnt    = (int*)  alloc((size_t)(N+1)*4);
  int*   offs   = (int*)  alloc((size_t)(N+1)*4);
  int*   cursor = (int*)  alloc((size_t)N*4);
  int*   bsums  = (int*)  alloc(1024);
  int*   csr    = (int*)  alloc((size_t)Ep*4);
  u16*   hb     = (u16*)  alloc((size_t)N*128*2);   // 12.8 MB bf16 gather operand
  float* x2     = (float*)alloc((size_t)N*128*4);   // 25.6 MB

  int n1 = N + 1;
  int zb = (n1 + 255)/256;
  int eb = (Ep + 255)/256;
  int sb = (n1 + 255)/256;
  int gb = (N + 31)/32;   // gemm: 32 rows / block (1563 blocks)
  int wb = (N + 3)/4;     // aggregate: 4 waves / block

  // CSR prefix
  r16_zero <<<zb, 256, 0, stream>>>(cnt, n1);
  r16_hist <<<eb, 256, 0, stream>>>(ei, E, Ep, cnt);
  r16_scan1<<<sb, 256, 0, stream>>>(cnt, n1, offs, bsums);
  r16_scan2<<<1, 256, 0, stream>>>(bsums, sb);
  r16_scan3<<<sb, 256, 0, stream>>>(offs, cnt, bsums, n1, N, offs, cursor);

  // FAT: layer-1 GEMM+dots co-scheduled with CSR fill
  r16_gemm_fill<<<gb + eb, 256, 0, stream>>>(x, W1, as1, ad1, hb, AS, AD, N, gb,
                                             ei, E, Ep, cursor, csr);
  r16_aggregate<<<wb, 256, 0, stream>>>(hb, AS, AD, offs, csr, b1, bng, bnb, bnm, bnv,
                                        x2, N, 1);
  // layer 2
  r16_gemm     <<<gb, 256, 0, stream>>>(x2, W2, as2, ad2, hb, AS, AD, N);
  r16_aggregate<<<wb, 256, 0, stream>>>(hb, AS, AD, offs, csr, b2, 0, 0, 0, 0,
                                        out, N, 0);
}

// Round 17
// 310.669 us; speedup vs baseline: 1.0077x; 1.0077x over previous
//
// rev r17 — MFMA GEMM (mfma_f32_16x16x32_bf16). r16 postmortem: f32 GEMM is
// W-load-duplication-bound (8 cohorts re-read same W; 32-row tile doubled W
// traffic: 52->77 µs). MFMA shares operands across lanes natively. W pre-
// transposed+bf16 (prep kernel); X f32->bf16 at LDS stage; LDS stride 136
// (2-way bank alias = free). Dots fused in epilogue. r15 best: 298 µs.
#include <hip/hip_runtime.h>

typedef unsigned short u16;
typedef unsigned int   u32;
typedef short v8s __attribute__((ext_vector_type(8)));   // 8 bf16 (4 VGPRs)
typedef float v4f __attribute__((ext_vector_type(4)));   // 4 f32 acc

__device__ __forceinline__ float b2f(u16 h){ return __uint_as_float(((u32)h) << 16); }
__device__ __forceinline__ u16   f2b(float f){
  u32 u = __float_as_uint(f);
  u32 r = u + 0x7FFFu + ((u >> 16) & 1u);   // round-to-nearest-even
  return (u16)(r >> 16);
}
__device__ __forceinline__ float lo16(u32 w){ return b2f((u16)(w & 0xFFFFu)); }
__device__ __forceinline__ float hi16(u32 w){ return b2f((u16)(w >> 16)); }

#define XS_STRIDE 136
#define WS_STRIDE 136

// ---------------- CSR build ----------------
__global__ void r17_zero(int* p, int n){
  int t = blockIdx.x*blockDim.x + threadIdx.x;
  if (t < n) p[t] = 0;
}

__global__ void r17_hist(const int* ei, int E, int Ep, int* cnt){
  int t = blockIdx.x*blockDim.x + threadIdx.x;
  if (t >= Ep) return;
  int dst = (t < E) ? ei[E + t] : (t - E);
  atomicAdd(&cnt[dst], 1);
}

__global__ void r17_scan1(const int* in, int n, int* incl, int* bsums){
  __shared__ int tmp[256];
  int t = threadIdx.x; int g = blockIdx.x*256 + t;
  int v = (g < n) ? in[g] : 0;
  tmp[t] = v; __syncthreads();
  for (int off = 1; off < 256; off <<= 1){
    int u = (t >= off) ? tmp[t - off] : 0;
    __syncthreads();
    tmp[t] += u;
    __syncthreads();
  }
  if (g < n) incl[g] = tmp[t];
  if (t == 255) bsums[blockIdx.x] = tmp[255];
}

__global__ void r17_scan2(int* bsums, int nb){
  __shared__ int tmp[256];
  int t = threadIdx.x;
  int v = (t < nb) ? bsums[t] : 0;
  tmp[t] = v; __syncthreads();
  for (int off = 1; off < 256; off <<= 1){
    int u = (t >= off) ? tmp[t - off] : 0;
    __syncthreads();
    tmp[t] += u;
    __syncthreads();
  }
  if (t < nb) bsums[t] = tmp[t];
}

__global__ void r17_scan3(const int* incl, const int* cnt, const int* bsums,
                          int n, int Nnodes, int* offs, int* cursor){
  int t = threadIdx.x; int b = blockIdx.x; int g = b*256 + t;
  if (g >= n) return;
  int add = (b > 0) ? bsums[b-1] : 0;
  int ex = incl[g] - cnt[g] + add;
  offs[g] = ex;
  if (g < Nnodes) cursor[g] = ex;
}

// ---- W prep: f32 [k][n] -> bf16 transposed [n][k] (B-fragment contiguous) ----
__global__ void r17_wprep(const float* __restrict__ W, u16* __restrict__ WT){
  int t = blockIdx.x*256 + threadIdx.x;   // 16384
  int k = t >> 7, n = t & 127;
  WT[n*128 + k] = f2b(W[k*128 + n]);
}

// ---- MFMA GEMM body: 64 rows x 128 cols, 4 waves x 16-row stripes ----
__device__ __forceinline__ void r17_gemm_body(
    const float* __restrict__ X, const u16* __restrict__ WT,
    const float* __restrict__ atts, const float* __restrict__ attd,
    u16* __restrict__ HB, float* __restrict__ AS, float* __restrict__ AD,
    int nrows, int blk, u16* xs, u16* ws){
  int t = threadIdx.x;
  int r0 = blk * 64;
  // stage X: 64x128 f32 -> bf16 LDS (stride 136)
  #pragma unroll
  for (int it = 0; it < 8; ++it){
    int idx = it*256 + t;        // float4 index; 32 per row
    int row = idx >> 5;
    int c4  = (idx & 31) * 4;
    float4 v = {0.f,0.f,0.f,0.f};
    if (r0 + row < nrows) v = *(const float4*)(X + (size_t)(r0+row)*128 + c4);
    u16* d = &xs[row*XS_STRIDE + c4];
    d[0]=f2b(v.x); d[1]=f2b(v.y); d[2]=f2b(v.z); d[3]=f2b(v.w);
  }
  // stage WT: 128x128 bf16 -> LDS (stride 136)
  #pragma unroll
  for (int it = 0; it < 8; ++it){
    int idx = it*256 + t;        // uint4 index; 16 per WT row
    int row = idx >> 4;
    int c8  = (idx & 15) * 8;
    *(uint4*)&ws[row*WS_STRIDE + c8] = *(const uint4*)&WT[row*128 + c8];
  }
  __syncthreads();

  int wv   = t >> 6;           // wave 0..3 -> 16-row stripe
  int lane = t & 63;
  int m    = lane & 15;
  int quad = lane >> 4;
  int rw   = wv * 16;

  v4f acc[8];
  #pragma unroll
  for (int ct = 0; ct < 8; ++ct) acc[ct] = (v4f){0.f,0.f,0.f,0.f};

  #pragma unroll
  for (int kb = 0; kb < 4; ++kb){
    v8s a = *(const v8s*)&xs[(rw + m)*XS_STRIDE + kb*32 + quad*8];
    #pragma unroll
    for (int ct = 0; ct < 8; ++ct){
      v8s b = *(const v8s*)&ws[(ct*16 + m)*WS_STRIDE + kb*32 + quad*8];
      acc[ct] = __builtin_amdgcn_mfma_f32_16x16x32_bf16(a, b, acc[ct], 0, 0, 0);
    }
  }

  // epilogue: dots (quad-local 16-lane reduce) + bf16 HB store
  // C/D: row = rw + quad*4 + reg, col = ct*16 + m
  float att_s[8], att_d[8];
  #pragma unroll
  for (int ct = 0; ct < 8; ++ct){
    att_s[ct] = atts[ct*16 + m];
    att_d[ct] = attd[ct*16 + m];
  }
  #pragma unroll
  for (int r = 0; r < 4; ++r){
    int row = r0 + rw + quad*4 + r;
    float ps = 0.f, pd = 0.f;
    #pragma unroll
    for (int ct = 0; ct < 8; ++ct){
      ps = fmaf(acc[ct][r], att_s[ct], ps);
      pd = fmaf(acc[ct][r], att_d[ct], pd);
    }
    #pragma unroll
    for (int off = 8; off >= 1; off >>= 1){   // reduce 16 lanes within quad
      ps += __shfl_xor(ps, off);
      pd += __shfl_xor(pd, off);
    }
    if (row < nrows){
      #pragma unroll
      for (int ct = 0; ct < 8; ++ct)
        HB[(size_t)row*128 + ct*16 + m] = f2b(acc[ct][r]);
      if (m == 0){ AS[row] = ps; AD[row] = pd; }
    }
  }
}

// FAT: blocks [0,gemmBlocks) = MFMA GEMM+dots; rest = CSR fill
__global__ __launch_bounds__(256)
void r17_gemm_fill(const float* __restrict__ X, const u16* __restrict__ WT,
                   const float* __restrict__ atts, const float* __restrict__ attd,
                   u16* __restrict__ HB, float* __restrict__ AS, float* __restrict__ AD,
                   int nrows, int gemmBlocks,
                   const int* __restrict__ ei, int E, int Ep,
                   int* cursor, int* csr_src){
  __shared__ u16 xs[64*XS_STRIDE];    // 17.4 KB
  __shared__ u16 ws[128*WS_STRIDE];   // 34.8 KB
  if ((int)blockIdx.x >= gemmBlocks){
    int g = ((int)blockIdx.x - gemmBlocks)*256 + threadIdx.x;
    if (g < Ep){
      int src, dst;
      if (g < E){ src = ei[g]; dst = ei[E + g]; } else { src = g - E; dst = g - E; }
      int pos = atomicAdd(&cursor[dst], 1);
      csr_src[pos] = src;
    }
    return;
  }
  r17_gemm_body(X, WT, atts, attd, HB, AS, AD, nrows, blockIdx.x, xs, ws);
}

__global__ __launch_bounds__(256)
void r17_gemm(const float* __restrict__ X, const u16* __restrict__ WT,
              const float* __restrict__ atts, const float* __restrict__ attd,
              u16* __restrict__ HB, float* __restrict__ AS, float* __restrict__ AD,
              int nrows){
  __shared__ u16 xs[64*XS_STRIDE];
  __shared__ u16 ws[128*WS_STRIDE];
  r17_gemm_body(X, WT, atts, attd, HB, AS, AD, nrows, blockIdx.x, xs, ws);
}

// ---- segment softmax + aggregation (one wave / dst node), unchanged r15 ----
__global__ __launch_bounds__(256)
void r17_aggregate(const u16* __restrict__ HB, const float* __restrict__ AS,
                   const float* __restrict__ AD,
                   const int* __restrict__ offs, const int* __restrict__ csr,
                   const float* __restrict__ bias,
                   const float* __restrict__ gamma_, const float* __restrict__ beta_,
                   const float* __restrict__ mean_, const float* __restrict__ var_,
                   float* __restrict__ outp, int n, int doBN){
  int wid  = (blockIdx.x*256 + threadIdx.x) >> 6;
  int lane = threadIdx.x & 63;
  if (wid >= n) return;
  int beg = offs[wid], end = offs[wid+1];
  int deg = end - beg;
  float ad = AD[wid];
  int c2 = lane*2;
  float a0 = 0.f, a1 = 0.f;

  if (deg <= 64){
    int   my_s = 0;
    float my_e = -3.0e38f;
    int myk = beg + lane;
    bool act = (myk < end);
    if (act){
      my_s = csr[myk];
      float e = AS[my_s] + ad;
      my_e = (e > 0.f) ? e : 0.2f*e;
    }
    float m = my_e;
    #pragma unroll
    for (int off = 32; off >= 1; off >>= 1) m = fmaxf(m, __shfl_xor(m, off));
    float pz = act ? __expf(my_e - m) : 0.f;
    float den = pz;
    #pragma unroll
    for (int off = 32; off >= 1; off >>= 1) den += __shfl_xor(den, off);
    float my_al = pz / (den + 1e-16f);

    int j = 0;
    for (; j + 8 <= deg; j += 8){
      int   s0 = __shfl(my_s, j),   s1 = __shfl(my_s, j+1);
      int   s2 = __shfl(my_s, j+2), s3 = __shfl(my_s, j+3);
      int   s4 = __shfl(my_s, j+4), s5 = __shfl(my_s, j+5);
      int   s6 = __shfl(my_s, j+6), s7 = __shfl(my_s, j+7);
      float l0 = __shfl(my_al, j),   l1 = __shfl(my_al, j+1);
      float l2 = __shfl(my_al, j+2), l3 = __shfl(my_al, j+3);
      float l4 = __shfl(my_al, j+4), l5 = __shfl(my_al, j+5);
      float l6 = __shfl(my_al, j+6), l7 = __shfl(my_al, j+7);
      u32 h0 = *(const u32*)&HB[(size_t)s0*128 + c2];
      u32 h1 = *(const u32*)&HB[(size_t)s1*128 + c2];
      u32 h2 = *(const u32*)&HB[(size_t)s2*128 + c2];
      u32 h3 = *(const u32*)&HB[(size_t)s3*128 + c2];
      u32 h4 = *(const u32*)&HB[(size_t)s4*128 + c2];
      u32 h5 = *(const u32*)&HB[(size_t)s5*128 + c2];
      u32 h6 = *(const u32*)&HB[(size_t)s6*128 + c2];
      u32 h7 = *(const u32*)&HB[(size_t)s7*128 + c2];
      a0 = fmaf(l0, lo16(h0), a0); a1 = fmaf(l0, hi16(h0), a1);
      a0 = fmaf(l1, lo16(h1), a0); a1 = fmaf(l1, hi16(h1), a1);
      a0 = fmaf(l2, lo16(h2), a0); a1 = fmaf(l2, hi16(h2), a1);
      a0 = fmaf(l3, lo16(h3), a0); a1 = fmaf(l3, hi16(h3), a1);
      a0 = fmaf(l4, lo16(h4), a0); a1 = fmaf(l4, hi16(h4), a1);
      a0 = fmaf(l5, lo16(h5), a0); a1 = fmaf(l5, hi16(h5), a1);
      a0 = fmaf(l6, lo16(h6), a0); a1 = fmaf(l6, hi16(h6), a1);
      a0 = fmaf(l7, lo16(h7), a0); a1 = fmaf(l7, hi16(h7), a1);
    }
    for (; j + 4 <= deg; j += 4){
      int   s0 = __shfl(my_s, j),   s1 = __shfl(my_s, j+1);
      int   s2 = __shfl(my_s, j+2), s3 = __shfl(my_s, j+3);
      float l0 = __shfl(my_al, j),   l1 = __shfl(my_al, j+1);
      float l2 = __shfl(my_al, j+2), l3 = __shfl(my_al, j+3);
      u32 h0 = *(const u32*)&HB[(size_t)s0*128 + c2];
      u32 h1 = *(const u32*)&HB[(size_t)s1*128 + c2];
      u32 h2 = *(const u32*)&HB[(size_t)s2*128 + c2];
      u32 h3 = *(const u32*)&HB[(size_t)s3*128 + c2];
      a0 = fmaf(l0, lo16(h0), a0); a1 = fmaf(l0, hi16(h0), a1);
      a0 = fmaf(l1, lo16(h1), a0); a1 = fmaf(l1, hi16(h1), a1);
      a0 = fmaf(l2, lo16(h2), a0); a1 = fmaf(l2, hi16(h2), a1);
      a0 = fmaf(l3, lo16(h3), a0); a1 = fmaf(l3, hi16(h3), a1);
    }
    for (; j < deg; ++j){
      int   s = __shfl(my_s, j);
      float l = __shfl(my_al, j);
      u32 hv = *(const u32*)&HB[(size_t)s*128 + c2];
      a0 = fmaf(l, lo16(hv), a0); a1 = fmaf(l, hi16(hv), a1);
    }
  } else {
    float m = -3.0e38f;
    for (int k = beg + lane; k < end; k += 64){
      int s = csr[k];
      float e = AS[s] + ad; e = (e > 0.f) ? e : 0.2f*e;
      m = fmaxf(m, e);
    }
    #pragma unroll
    for (int off = 32; off >= 1; off >>= 1) m = fmaxf(m, __shfl_xor(m, off));
    float den = 0.f;
    for (int k = beg + lane; k < end; k += 64){
      int s = csr[k];
      float e = AS[s] + ad; e = (e > 0.f) ? e : 0.2f*e;
      den += __expf(e - m);
    }
    #pragma unroll
    for (int off = 32; off >= 1; off >>= 1) den += __shfl_xor(den, off);
    float inv = 1.0f / (den + 1e-16f);
    for (int k = beg; k < end; ++k){
      int s = csr[k];
      float e = AS[s] + ad; e = (e > 0.f) ? e : 0.2f*e;
      float al = __expf(e - m) * inv;
      u32 hv = *(const u32*)&HB[(size_t)s*128 + c2];
      a0 = fmaf(al, lo16(hv), a0); a1 = fmaf(al, hi16(hv), a1);
    }
  }

  float v0 = a0 + bias[c2];
  float v1 = a1 + bias[c2+1];
  v0 = fmaxf(v0, 0.f); v1 = fmaxf(v1, 0.f);            // relu
  if (doBN){
    float s0 = gamma_[c2]   * rsqrtf(var_[c2]   + 1e-5f);
    float s1 = gamma_[c2+1] * rsqrtf(var_[c2+1] + 1e-5f);
    v0 = (v0 - mean_[c2])*s0   + beta_[c2];
    v1 = (v1 - mean_[c2+1])*s1 + beta_[c2+1];
  }
  float2 o = {v0, v1};
  ((float2*)(outp + (size_t)wid*128))[lane] = o;
}

extern "C" void kernel_launch(void* const* d_in, const int* in_sizes, int n_in,
                              void* d_out, int out_size, void* d_ws, size_t ws_size,
                              hipStream_t stream){
  const float* x   = (const float*)d_in[0];
  const int*   ei  = (const int*)  d_in[1];
  const float* W1  = (const float*)d_in[2];
  const float* as1 = (const float*)d_in[3];
  const float* ad1 = (const float*)d_in[4];
  const float* b1  = (const float*)d_in[5];
  const float* bng = (const float*)d_in[6];
  const float* bnb = (const float*)d_in[7];
  const float* bnm = (const float*)d_in[8];
  const float* bnv = (const float*)d_in[9];
  const float* W2  = (const float*)d_in[10];
  const float* as2 = (const float*)d_in[11];
  const float* ad2 = (const float*)d_in[12];
  const float* b2  = (const float*)d_in[13];
  float* out = (float*)d_out;

  int N  = in_sizes[0] / 128;
  int E  = in_sizes[1] / 2;
  int Ep = E + N;
  if (N <= 0 || E <= 0) return;

  char* base = (char*)d_ws;
  size_t off = 0;
  auto alloc = [&](size_t bytes)->char*{
    off = (off + 255) & ~(size_t)255;
    char* q = base + off; off += bytes; return q;
  };
  float* AS     = (float*)alloc((size_t)N*4);
  float* AD     = (float*)alloc((size_t)N*4);
  int*   cnt    = (int*)  alloc((size_t)(N+1)*4);
  int*   offs   = (int*)  alloc((size_t)(N+1)*4);
  int*   cursor = (int*)  alloc((size_t)N*4);
  int*   bsums  = (int*)  alloc(1024);
  int*   csr    = (int*)  alloc((size_t)Ep*4);
  u16*   WT1    = (u16*)  alloc(16384*2);
  u16*   WT2    = (u16*)  alloc(16384*2);
  u16*   hb     = (u16*)  alloc((size_t)N*128*2);   // bf16 gather operand
  float* x2     = (float*)alloc((size_t)N*128*4);

  int n1 = N + 1;
  int zb = (n1 + 255)/256;
  int eb = (Ep + 255)/256;
  int sb = (n1 + 255)/256;
  int gb = (N + 63)/64;   // MFMA gemm: 64 rows / block
  int wb = (N + 3)/4;

  // W prep (tiny) + CSR prefix
  r17_wprep<<<64, 256, 0, stream>>>(W1, WT1);
  r17_wprep<<<64, 256, 0, stream>>>(W2, WT2);
  r17_zero <<<zb, 256, 0, stream>>>(cnt, n1);
  r17_hist <<<eb, 256, 0, stream>>>(ei, E, Ep, cnt);
  r17_scan1<<<sb, 256, 0, stream>>>(cnt, n1, offs, bsums);
  r17_scan2<<<1, 256, 0, stream>>>(bsums, sb);
  r17_scan3<<<sb, 256, 0, stream>>>(offs, cnt, bsums, n1, N, offs, cursor);

  // FAT: layer-1 MFMA GEMM+dots co-scheduled with CSR fill
  r17_gemm_fill<<<gb + eb, 256, 0, stream>>>(x, WT1, as1, ad1, hb, AS, AD, N, gb,
                                             ei, E, Ep, cursor, csr);
  r17_aggregate<<<wb, 256, 0, stream>>>(hb, AS, AD, offs, csr, b1, bng, bnb, bnm, bnv,
                                        x2, N, 1);
  // layer 2
  r17_gemm     <<<gb, 256, 0, stream>>>(x2, WT2, as2, ad2, hb, AS, AD, N);
  r17_aggregate<<<wb, 256, 0, stream>>>(hb, AS, AD, offs, csr, b2, 0, 0, 0, 0,
                                        out, N, 0);
}